// Round 5
// baseline (2379.128 us; speedup 1.0000x reference)
//
#include <hip/hip_runtime.h>
#include <math.h>

#define BS_   2
#define S_    1728
#define C_    384
#define H_    8
#define HD_   48
#define DFFN_ 1536
#define NQ_   300
#define GD_   12

typedef __attribute__((ext_vector_type(8))) short short8;
typedef __attribute__((ext_vector_type(4))) float f32x4;

__device__ __forceinline__ ushort f2bf(float f) {
    union { float f; uint u; } v; v.f = f;
    uint u = v.u;
    uint r = (u + 0x7FFFu + ((u >> 16) & 1u)) >> 16;  // RNE
    return (ushort)r;
}
__device__ __forceinline__ float bf2f(ushort h) {
    union { uint u; float f; } v; v.u = ((uint)h) << 16;
    return v.f;
}

// ======================= one-shot fp32 -> bf16 weight conversion =======================
#define CT_N 34
struct ConvTab {
    const float* src[CT_N];
    ushort* dst[CT_N];
    int n[CT_N];
    int cum[CT_N + 1];
};
__global__ __launch_bounds__(256) void convall_kernel(ConvTab t)
{
    int blk = blockIdx.x;
    int e = 0;
    while (blk >= t.cum[e + 1]) ++e;
    int local = blk - t.cum[e];
    int base = local * 2048 + (int)threadIdx.x * 8;
    if (base >= t.n[e]) return;
    const float* s = t.src[e] + base;
    float4 a = *(const float4*)s;
    float4 b = *(const float4*)(s + 4);
    short8 o;
    o[0] = (short)f2bf(a.x); o[1] = (short)f2bf(a.y);
    o[2] = (short)f2bf(a.z); o[3] = (short)f2bf(a.w);
    o[4] = (short)f2bf(b.x); o[5] = (short)f2bf(b.y);
    o[6] = (short)f2bf(b.z); o[7] = (short)f2bf(b.w);
    *(short8*)(t.dst[e] + base) = o;
}

__global__ __launch_bounds__(256) void biaspack_kernel(
    const float* __restrict__ eoff, const float* __restrict__ eaw,
    const float* __restrict__ doff, const float* __restrict__ daw,
    float* __restrict__ be, float* __restrict__ bd)
{
    int i = blockIdx.x * 256 + threadIdx.x;
    if (i >= 768) return;
    int l = i >> 7, p = i & 127;
    be[i] = (p < 96) ? eoff[l * 96 + p] : eaw[l * 32 + p - 96];
    bd[i] = (p < 96) ? doff[l * 96 + p] : daw[l * 32 + p - 96];
}

// ======================= bf16 MFMA GEMM, tile 128x64, 4 waves of 64x32 =======================
// AMODE 0: A = bf16 ptr [M,K].  AMODE 1: A = f2bf(a0f[gm*K+k] + A1[(gm%rowmod)*lda1+k]).
// W bf16 [N,K]; bias fp32 [N]; out fp32 or bf16 (flags&2), relu (flags&1).
template<int AMODE>
__global__ __launch_bounds__(256) void gemm128_kernel(
    const void* __restrict__ Aptr, const float* __restrict__ A1,
    int lda1, int rowmod,
    const ushort* __restrict__ W, const float* __restrict__ bias,
    void* __restrict__ Co, int M, int N, int K, int flags)
{
    __shared__ __align__(16) ushort As[128][40];
    __shared__ __align__(16) ushort Ws[64][40];

    const int tid = threadIdx.x;
    const int m0 = blockIdx.y * 128;
    const int n0 = blockIdx.x * 64;

    const int arow = tid >> 1;
    const int acol = (tid & 1) * 16;
    const int gmA = m0 + arow;
    const int wrow = tid >> 2;
    const int wcol = (tid & 3) * 8;
    const int gnW = n0 + wrow;

    const int lane = tid & 63;
    const int w = tid >> 6;
    const int wm = (w >> 1) * 64;
    const int wn = (w & 1) * 32;
    const int fr = lane & 15;
    const int fq = lane >> 4;

    const ushort* Ab = (const ushort*)Aptr;
    const float* a0f = (const float*)Aptr;
    int a1row = 0;
    if (AMODE == 1 && gmA < M) a1row = gmA % rowmod;

    f32x4 acc[4][2] = {};

    short8 va[2] = {}, vw = {};
    if (gmA < M) {
        if (AMODE == 0) {
            va[0] = *(const short8*)(Ab + (size_t)gmA * K + acol);
            va[1] = *(const short8*)(Ab + (size_t)gmA * K + acol + 8);
        } else {
            const float* p0 = a0f + (size_t)gmA * K + acol;
            const float* p1 = A1 + (size_t)a1row * lda1 + acol;
            #pragma unroll
            for (int c = 0; c < 2; ++c)
                #pragma unroll
                for (int j = 0; j < 8; ++j)
                    va[c][j] = (short)f2bf(p0[c * 8 + j] + p1[c * 8 + j]);
        }
    }
    if (gnW < N) vw = *(const short8*)(W + (size_t)gnW * K + wcol);

    for (int k0 = 0; k0 < K; k0 += 32) {
        *(short8*)&As[arow][acol] = va[0];
        *(short8*)&As[arow][acol + 8] = va[1];
        *(short8*)&Ws[wrow][wcol] = vw;
        __syncthreads();
        if (k0 + 32 < K) {
            if (gmA < M) {
                if (AMODE == 0) {
                    va[0] = *(const short8*)(Ab + (size_t)gmA * K + k0 + 32 + acol);
                    va[1] = *(const short8*)(Ab + (size_t)gmA * K + k0 + 32 + acol + 8);
                } else {
                    const float* p0 = a0f + (size_t)gmA * K + k0 + 32 + acol;
                    const float* p1 = A1 + (size_t)a1row * lda1 + k0 + 32 + acol;
                    #pragma unroll
                    for (int c = 0; c < 2; ++c)
                        #pragma unroll
                        for (int j = 0; j < 8; ++j)
                            va[c][j] = (short)f2bf(p0[c * 8 + j] + p1[c * 8 + j]);
                }
            }
            if (gnW < N) vw = *(const short8*)(W + (size_t)gnW * K + k0 + 32 + wcol);
        }
        short8 af[4], bw[2];
        #pragma unroll
        for (int fi = 0; fi < 4; ++fi)
            af[fi] = *(const short8*)&As[wm + fi * 16 + fr][fq * 8];
        #pragma unroll
        for (int ni = 0; ni < 2; ++ni)
            bw[ni] = *(const short8*)&Ws[wn + ni * 16 + fr][fq * 8];
        #pragma unroll
        for (int fi = 0; fi < 4; ++fi)
            #pragma unroll
            for (int ni = 0; ni < 2; ++ni)
                acc[fi][ni] = __builtin_amdgcn_mfma_f32_16x16x32_bf16(
                    af[fi], bw[ni], acc[fi][ni], 0, 0, 0);
        __syncthreads();
    }

    const int relu = flags & 1;
    const int obf = flags & 2;
    float* Cf = (float*)Co;
    ushort* Ch = (ushort*)Co;
    #pragma unroll
    for (int fi = 0; fi < 4; ++fi) {
        #pragma unroll
        for (int ni = 0; ni < 2; ++ni) {
            int gn = n0 + wn + ni * 16 + fr;
            if (gn >= N) continue;
            float bv = bias[gn];
            #pragma unroll
            for (int j = 0; j < 4; ++j) {
                int gm = m0 + wm + fi * 16 + fq * 4 + j;
                if (gm >= M) continue;
                float v = acc[fi][ni][j] + bv;
                if (relu) v = fmaxf(v, 0.f);
                if (obf) Ch[(size_t)gm * N + gn] = f2bf(v);
                else     Cf[(size_t)gm * N + gn] = v;
            }
        }
    }
}

// ======================= fused MHA (decoder self-attn) =======================
// qk fp32 [B*300, 768] (cols 0..383 Q, 384..767 K); vpb fp32 [B*300,384]; out bf16.
// NOTE: every LDS byte the MFMAs read MUST be written (zero-padded) — 0xNaN garbage
// times a zero operand still produces NaN through MFMA.
__global__ __launch_bounds__(256) void mha_fused_kernel(
    const float* __restrict__ qk, const float* __restrict__ vpb,
    ushort* __restrict__ out)
{
    __shared__ __align__(16) ushort kv[20480];       // K[320][64] then Vt[48][320] (bf16, swizzled)
    __shared__ __align__(16) ushort pbuf[4][640];    // per-wave P [16][40]

    const int qt = blockIdx.x;
    const int bh = blockIdx.y;
    const int b = bh >> 3, h = bh & 7;
    const int tid = threadIdx.x;
    const int lane = tid & 63, wv = tid >> 6;
    const int fr = lane & 15, fq = lane >> 4;

    // ---- stage K: kv[key][d] for key<320, d<64 (zero pad outside 300x48) ----
    const float* kbase = qk + (size_t)b * 300 * 768 + 384 + h * 48;
    for (int idx = tid; idx < 320 * 64; idx += 256) {
        int key = idx >> 6, d = idx & 63;
        int byte = (key * 128 + d * 2) ^ ((key & 7) << 4);
        ushort v = 0;
        if (key < 300 && d < 48) v = f2bf(kbase[(size_t)key * 768 + d]);
        *(ushort*)((char*)kv + byte) = v;
    }

    int q = qt * 64 + wv * 16 + fr;
    short8 aq[2] = {short8{}, short8{}};
    if (q < 300) {
        const float* qrow = qk + ((size_t)(b * 300 + q)) * 768 + h * 48;
        #pragma unroll
        for (int half = 0; half < 2; ++half)
            #pragma unroll
            for (int j = 0; j < 8; ++j) {
                int d = half * 32 + fq * 8 + j;
                if (d < 48) aq[half][j] = (short)f2bf(qrow[d]);
            }
    }
    __syncthreads();

    f32x4 sfr[20];
    #pragma unroll
    for (int t = 0; t < 20; ++t) {
        int key = t * 16 + fr;
        short8 bk[2];
        #pragma unroll
        for (int half = 0; half < 2; ++half) {
            int byte = (key * 128 + (half * 32 + fq * 8) * 2) ^ ((key & 7) << 4);
            bk[half] = *(const short8*)((const char*)kv + byte);
        }
        f32x4 c = {};
        c = __builtin_amdgcn_mfma_f32_16x16x32_bf16(aq[0], bk[0], c, 0, 0, 0);
        c = __builtin_amdgcn_mfma_f32_16x16x32_bf16(aq[1], bk[1], c, 0, 0, 0);
        sfr[t] = c;
    }
    if (fr >= 12) { sfr[18][0] = sfr[18][1] = sfr[18][2] = sfr[18][3] = -1e30f; }
    sfr[19][0] = sfr[19][1] = sfr[19][2] = sfr[19][3] = -1e30f;

    const float scale = 0.14433756729740643f;  // 1/sqrt(48)
    float m[4], l[4];
    #pragma unroll
    for (int j = 0; j < 4; ++j) {
        float mm = -1e30f;
        #pragma unroll
        for (int t = 0; t < 20; ++t) mm = fmaxf(mm, sfr[t][j]);
        #pragma unroll
        for (int msk = 1; msk < 16; msk <<= 1) mm = fmaxf(mm, __shfl_xor(mm, msk));
        m[j] = mm;
    }
    #pragma unroll
    for (int j = 0; j < 4; ++j) {
        float ss = 0.f;
        #pragma unroll
        for (int t = 0; t < 20; ++t) {
            float p = __expf((sfr[t][j] - m[j]) * scale);
            sfr[t][j] = p;
            ss += p;
        }
        #pragma unroll
        for (int msk = 1; msk < 16; msk <<= 1) ss += __shfl_xor(ss, msk);
        l[j] = ss;
    }

    __syncthreads();
    // ---- stage Vt: kv[d][key] for d<48, key<320 (zero pad key>=300) ----
    const float* vbase = vpb + (size_t)b * 300 * 384 + h * 48;
    for (int idx = tid; idx < 48 * 320; idx += 256) {
        int d = idx / 320, key = idx - d * 320;
        int byte = (d * 640 + key * 2) ^ ((d & 7) << 4);
        ushort v = 0;
        if (key < 300) v = f2bf(vbase[(size_t)key * 384 + d]);
        *(ushort*)((char*)kv + byte) = v;
    }
    __syncthreads();

    f32x4 o0 = {}, o1 = {}, o2 = {};
    ushort* pw = &pbuf[wv][0];
    for (int ch = 0; ch < 10; ++ch) {
        #pragma unroll
        for (int tt = 0; tt < 2; ++tt) {
            int t = 2 * ch + tt;
            #pragma unroll
            for (int j = 0; j < 4; ++j)
                pw[(fq * 4 + j) * 40 + tt * 16 + fr] = f2bf(sfr[t][j]);
        }
        asm volatile("s_waitcnt lgkmcnt(0)" ::: "memory");
        short8 pa = *(const short8*)&pw[fr * 40 + fq * 8];
        short8 bv[3];
        #pragma unroll
        for (int dt = 0; dt < 3; ++dt) {
            int d = dt * 16 + fr;
            int byte = (d * 640 + (ch * 32 + fq * 8) * 2) ^ ((d & 7) << 4);
            bv[dt] = *(const short8*)((const char*)kv + byte);
        }
        o0 = __builtin_amdgcn_mfma_f32_16x16x32_bf16(pa, bv[0], o0, 0, 0, 0);
        o1 = __builtin_amdgcn_mfma_f32_16x16x32_bf16(pa, bv[1], o1, 0, 0, 0);
        o2 = __builtin_amdgcn_mfma_f32_16x16x32_bf16(pa, bv[2], o2, 0, 0, 0);
    }

    #pragma unroll
    for (int j = 0; j < 4; ++j) {
        int qq = qt * 64 + wv * 16 + fq * 4 + j;
        if (qq >= 300) continue;
        float invl = 1.f / l[j];
        ushort* orow = out + ((size_t)(b * 300 + qq)) * 384 + h * 48;
        orow[fr]      = f2bf(o0[j] * invl);
        orow[16 + fr] = f2bf(o1[j] * invl);
        orow[32 + fr] = f2bf(o2[j] * invl);
    }
}

// ======================= LayerNorm(res + delta), C=384, one wave/row =======================
__global__ __launch_bounds__(64) void ln_kernel(
    const float* __restrict__ res, const float* __restrict__ delta,
    const float* __restrict__ g, const float* __restrict__ b,
    float* __restrict__ out, ushort* __restrict__ out_bf)
{
    const int row = blockIdx.x;
    const int lane = threadIdx.x;
    const float* r = res + (size_t)row * C_;
    const float* d = delta + (size_t)row * C_;
    float vals[6];
    float s = 0.f;
    #pragma unroll
    for (int i = 0; i < 6; ++i) {
        int c = lane + 64 * i;
        vals[i] = r[c] + d[c];
        s += vals[i];
    }
    #pragma unroll
    for (int off = 32; off; off >>= 1) s += __shfl_xor(s, off);
    float mean = s * (1.f / C_);
    float vs = 0.f;
    #pragma unroll
    for (int i = 0; i < 6; ++i) { float t = vals[i] - mean; vs += t * t; }
    #pragma unroll
    for (int off = 32; off; off >>= 1) vs += __shfl_xor(vs, off);
    float rstd = rsqrtf(vs * (1.f / C_) + 1e-5f);
    float* o = out + (size_t)row * C_;
    ushort* ob = out_bf + (size_t)row * C_;
    #pragma unroll
    for (int i = 0; i < 6; ++i) {
        int c = lane + 64 * i;
        float v = (vals[i] - mean) * rstd * g[c] + b[c];
        o[c] = v;
        ob[c] = f2bf(v);
    }
}

// ======================= MSDA sampling (bf16 value, merged off/aw input) =======================
__global__ __launch_bounds__(384) void msda_kernel(
    const ushort* __restrict__ value,  // (B,S,384) bf16
    const float* __restrict__ offaw,   // (B,Lq,128): 0..95 off, 96..127 aw
    const float* __restrict__ ref,     // (Lq,3)
    ushort* __restrict__ out,          // (B,Lq,384) bf16
    int Lq)
{
    const int bq = blockIdx.x;
    const int b = bq / Lq, qi = bq % Lq;
    const int t = threadIdx.x;
    const int h = t / HD_, c = t % HD_;

    const float* row = offaw + ((size_t)(b * Lq + qi)) * 128;
    const float* aw = row + 96 + h * 4;
    float a0 = aw[0], a1 = aw[1], a2 = aw[2], a3 = aw[3];
    float mx = fmaxf(fmaxf(a0, a1), fmaxf(a2, a3));
    float e0 = __expf(a0 - mx), e1 = __expf(a1 - mx), e2 = __expf(a2 - mx), e3 = __expf(a3 - mx);
    float inv = 1.f / (e0 + e1 + e2 + e3);
    float wgt[4] = { e0 * inv, e1 * inv, e2 * inv, e3 * inv };

    const float* off = row + h * 12;
    float rx = ref[qi * 3 + 0], ry = ref[qi * 3 + 1], rz = ref[qi * 3 + 2];
    const ushort* vb = value + (size_t)b * S_ * C_ + h * HD_ + c;

    float acc = 0.f;
    #pragma unroll
    for (int p = 0; p < 4; ++p) {
        float x = (rx + off[p * 3 + 0] * (1.f / GD_)) * GD_ - 0.5f;
        float y = (ry + off[p * 3 + 1] * (1.f / GD_)) * GD_ - 0.5f;
        float z = (rz + off[p * 3 + 2] * (1.f / GD_)) * GD_ - 0.5f;
        float x0f = floorf(x), y0f = floorf(y), z0f = floorf(z);
        float fx = x - x0f, fy = y - y0f, fz = z - z0f;
        int x0 = (int)x0f, y0 = (int)y0f, z0 = (int)z0f;
        float pv = 0.f;
        #pragma unroll
        for (int dz = 0; dz < 2; ++dz) {
            int zi = z0 + dz;
            if (zi < 0 || zi >= GD_) continue;
            float wz = dz ? fz : 1.f - fz;
            #pragma unroll
            for (int dy = 0; dy < 2; ++dy) {
                int yi = y0 + dy;
                if (yi < 0 || yi >= GD_) continue;
                float wy = dy ? fy : 1.f - fy;
                #pragma unroll
                for (int dx = 0; dx < 2; ++dx) {
                    int xi = x0 + dx;
                    if (xi < 0 || xi >= GD_) continue;
                    float wx = dx ? fx : 1.f - fx;
                    int s = (zi * GD_ + yi) * GD_ + xi;
                    pv += wz * wy * wx * bf2f(vb[(size_t)s * C_]);
                }
            }
        }
        acc += wgt[p] * pv;
    }
    out[((size_t)(b * Lq + qi)) * C_ + t] = f2bf(acc);
}

// ======================= misc =======================
__global__ __launch_bounds__(256) void prep_kernel(
    const float* __restrict__ srcs, const float* __restrict__ posin,
    const float* __restrict__ lvl, float* __restrict__ x, ushort* __restrict__ x_bf,
    float* __restrict__ pos)
{
    int idx = blockIdx.x * 256 + threadIdx.x;
    const int total = BS_ * S_ * C_;
    if (idx >= total) return;
    int c = idx % C_; int r = idx / C_;
    int s = r % S_;   int b = r / S_;
    size_t si = ((size_t)b * C_ + c) * S_ + s;
    float xv = srcs[si];
    x[idx] = xv;
    x_bf[idx] = f2bf(xv);
    pos[idx] = posin[si] + lvl[c];
}

__global__ __launch_bounds__(64) void encref_kernel(float* __restrict__ eref)
{
    int s = blockIdx.x * 64 + threadIdx.x;
    if (s >= S_) return;
    int w = s % GD_, h = (s / GD_) % GD_, d = s / (GD_ * GD_);
    eref[s * 3 + 0] = (w + 0.5f) / GD_;
    eref[s * 3 + 1] = (h + 0.5f) / GD_;
    eref[s * 3 + 2] = (d + 0.5f) / GD_;
}

__global__ __launch_bounds__(64) void decref_kernel(
    const float* __restrict__ qemb, const float* __restrict__ rw,
    const float* __restrict__ rb, float* __restrict__ dref)
{
    int idx = blockIdx.x * 64 + threadIdx.x;
    if (idx >= NQ_ * 3) return;
    int d = idx % 3, q = idx / 3;
    const float* qe = qemb + (size_t)q * 768;
    const float* w = rw + d * C_;
    float s = rb[d];
    for (int c = 0; c < C_; ++c) s = fmaf(qe[c], w[c], s);
    dref[idx] = 1.f / (1.f + __expf(-s));
}

__global__ __launch_bounds__(256) void init_y_kernel(
    const float* __restrict__ qemb, float* __restrict__ y, ushort* __restrict__ y_bf)
{
    int idx = blockIdx.x * 256 + threadIdx.x;
    const int total = BS_ * NQ_ * C_;
    if (idx >= total) return;
    int c = idx % C_; int q = (idx / C_) % NQ_;
    float v = qemb[(size_t)q * 768 + 384 + c];
    y[idx] = v;
    y_bf[idx] = f2bf(v);
}

// ======================= host =======================
static inline void gemm0(const ushort* A, const ushort* W, const float* bias, void* C,
                         int M, int N, int K, int flags, hipStream_t s)
{
    dim3 g((N + 63) / 64, (M + 127) / 128);
    hipLaunchKernelGGL(gemm128_kernel<0>, g, dim3(256), 0, s,
                       (const void*)A, (const float*)nullptr, 0, 1, W, bias, C, M, N, K, flags);
}
static inline void gemm1(const float* A0, const float* A1, int lda1, int rowmod,
                         const ushort* W, const float* bias, void* C,
                         int M, int N, int K, int flags, hipStream_t s)
{
    dim3 g((N + 63) / 64, (M + 127) / 128);
    hipLaunchKernelGGL(gemm128_kernel<1>, g, dim3(256), 0, s,
                       (const void*)A0, A1, lda1, rowmod, W, bias, C, M, N, K, flags);
}

extern "C" void kernel_launch(void* const* d_in, const int* in_sizes, int n_in,
                              void* d_out, int out_size, void* d_ws, size_t ws_size,
                              hipStream_t stream)
{
    const float* srcs    = (const float*)d_in[0];
    const float* qemb    = (const float*)d_in[2];
    const float* posin   = (const float*)d_in[3];
    const float* lvl     = (const float*)d_in[4];
    const float* ref_w   = (const float*)d_in[5];
    const float* ref_b   = (const float*)d_in[6];
    const float* e_off_w = (const float*)d_in[7];
    const float* e_off_b = (const float*)d_in[8];
    const float* e_aw_w  = (const float*)d_in[9];
    const float* e_aw_b  = (const float*)d_in[10];
    const float* e_vp_w  = (const float*)d_in[11];
    const float* e_vp_b  = (const float*)d_in[12];
    const float* e_op_w  = (const float*)d_in[13];
    const float* e_op_b  = (const float*)d_in[14];
    const float* e_n1_g  = (const float*)d_in[15];
    const float* e_n1_b  = (const float*)d_in[16];
    const float* e_l1_w  = (const float*)d_in[17];
    const float* e_l1_b  = (const float*)d_in[18];
    const float* e_l2_w  = (const float*)d_in[19];
    const float* e_l2_b  = (const float*)d_in[20];
    const float* e_n2_g  = (const float*)d_in[21];
    const float* e_n2_b  = (const float*)d_in[22];
    const float* dd_off_w = (const float*)d_in[23];
    const float* dd_off_b = (const float*)d_in[24];
    const float* dd_aw_w  = (const float*)d_in[25];
    const float* dd_aw_b  = (const float*)d_in[26];
    const float* dd_vp_w  = (const float*)d_in[27];
    const float* dd_vp_b  = (const float*)d_in[28];
    const float* dd_op_w  = (const float*)d_in[29];
    const float* dd_op_b  = (const float*)d_in[30];
    const float* dd_n1_g  = (const float*)d_in[31];
    const float* dd_n1_b  = (const float*)d_in[32];
    const float* dd_l1_w  = (const float*)d_in[33];
    const float* dd_l1_b  = (const float*)d_in[34];
    const float* dd_l2_w  = (const float*)d_in[35];
    const float* dd_l2_b  = (const float*)d_in[36];
    const float* dd_n2_g  = (const float*)d_in[37];
    const float* dd_n2_b  = (const float*)d_in[38];
    const float* dd_sa_in_w  = (const float*)d_in[39];
    const float* dd_sa_in_b  = (const float*)d_in[40];
    const float* dd_sa_out_w = (const float*)d_in[41];
    const float* dd_sa_out_b = (const float*)d_in[42];
    const float* dd_n3_g  = (const float*)d_in[43];
    const float* dd_n3_b  = (const float*)d_in[44];

    // ---------- workspace ----------
    float* ws = (float*)d_ws;
    size_t o = 0;
    const size_t NXC = (size_t)BS_ * S_ * C_;   // 1,327,104
    const size_t NYC = (size_t)BS_ * NQ_ * C_;  // 230,400
    float* x      = ws + o; o += NXC;
    float* pos    = ws + o; o += NXC;
    float* x2     = ws + o; o += NXC;
    float* offawE = ws + o; o += (size_t)BS_ * S_ * 128;
    float* qk     = ws + o; o += (size_t)BS_ * NQ_ * 768;
    float* vpb    = ws + o; o += NYC;
    float* y      = ws + o; o += NYC;
    float* eref   = ws + o; o += (size_t)S_ * 3 + 64;
    float* dref   = ws + o; o += (size_t)NQ_ * 3 + 64;
    float* offawBe = ws + o; o += 768;
    float* offawBd = ws + o; o += 768;
    o = (o + 7) & ~(size_t)7;

    ushort* bws = (ushort*)(ws + o);
    size_t ob = 0;
    ushort* x_bf    = bws + ob; ob += NXC;
    ushort* samp_bf = bws + ob; ob += NXC;
    ushort* hbuf_bf = bws + ob; ob += (size_t)BS_ * S_ * DFFN_;
    ushort* y_bf    = bws + ob; ob += NYC;
    ushort* value   = bws + ob; ob += NXC;
    const size_t SZ_OFFAW = (size_t)6 * 128 * C_;
    const size_t SZ_SQ    = (size_t)6 * C_ * C_;
    const size_t SZ_L1    = (size_t)6 * DFFN_ * C_;
    ushort* wOffawE = bws + ob; ob += SZ_OFFAW;
    ushort* wOffawD = bws + ob; ob += SZ_OFFAW;
    ushort* wVpE = bws + ob; ob += SZ_SQ;
    ushort* wOpE = bws + ob; ob += SZ_SQ;
    ushort* wL1E = bws + ob; ob += SZ_L1;
    ushort* wL2E = bws + ob; ob += SZ_L1;
    ushort* wVpD = bws + ob; ob += SZ_SQ;
    ushort* wOpD = bws + ob; ob += SZ_SQ;
    ushort* wL1D = bws + ob; ob += SZ_L1;
    ushort* wL2D = bws + ob; ob += SZ_L1;
    ushort* wSaIn = bws + ob; ob += (size_t)6 * 3 * C_ * C_;
    ushort* wSaOut = bws + ob; ob += SZ_SQ;

    // ---------- one-shot weight conversion ----------
    ConvTab ct;
    int ne = 0;
    auto addent = [&](const float* s, ushort* d, int n) {
        ct.src[ne] = s; ct.dst[ne] = d; ct.n[ne] = n; ++ne;
    };
    for (int l = 0; l < 6; ++l) addent(e_off_w + (size_t)l * 96 * C_, wOffawE + (size_t)l * 128 * C_, 96 * C_);
    for (int l = 0; l < 6; ++l) addent(e_aw_w + (size_t)l * 32 * C_, wOffawE + (size_t)l * 128 * C_ + 96 * C_, 32 * C_);
    for (int l = 0; l < 6; ++l) addent(dd_off_w + (size_t)l * 96 * C_, wOffawD + (size_t)l * 128 * C_, 96 * C_);
    for (int l = 0; l < 6; ++l) addent(dd_aw_w + (size_t)l * 32 * C_, wOffawD + (size_t)l * 128 * C_ + 96 * C_, 32 * C_);
    addent(e_vp_w, wVpE, (int)SZ_SQ);
    addent(e_op_w, wOpE, (int)SZ_SQ);
    addent(e_l1_w, wL1E, (int)SZ_L1);
    addent(e_l2_w, wL2E, (int)SZ_L1);
    addent(dd_vp_w, wVpD, (int)SZ_SQ);
    addent(dd_op_w, wOpD, (int)SZ_SQ);
    addent(dd_l1_w, wL1D, (int)SZ_L1);
    addent(dd_l2_w, wL2D, (int)SZ_L1);
    addent(dd_sa_in_w, wSaIn, (int)((size_t)6 * 3 * C_ * C_));
    addent(dd_sa_out_w, wSaOut, (int)SZ_SQ);
    ct.cum[0] = 0;
    for (int e = 0; e < CT_N; ++e) ct.cum[e + 1] = ct.cum[e] + (ct.n[e] + 2047) / 2048;
    hipLaunchKernelGGL(convall_kernel, dim3(ct.cum[CT_N]), dim3(256), 0, stream, ct);
    hipLaunchKernelGGL(biaspack_kernel, dim3(3), dim3(256), 0, stream,
                       e_off_b, e_aw_b, dd_off_b, dd_aw_b, offawBe, offawBd);

    const int nEnc = BS_ * S_ * C_;
    const int encBlocks = (nEnc + 255) / 256;
    const int nDec = BS_ * NQ_ * C_;
    const int decBlocks = (nDec + 255) / 256;

    hipLaunchKernelGGL(prep_kernel, dim3(encBlocks), dim3(256), 0, stream, srcs, posin, lvl, x, x_bf, pos);
    hipLaunchKernelGGL(encref_kernel, dim3((S_ + 63) / 64), dim3(64), 0, stream, eref);

    // ---- encoder ----
    for (int l = 0; l < 6; ++l) {
        gemm0(x_bf, wVpE + (size_t)l * C_ * C_, e_vp_b + (size_t)l * C_, value,
              BS_ * S_, C_, C_, 2, stream);
        gemm1(x, pos, C_, BS_ * S_, wOffawE + (size_t)l * 128 * C_, offawBe + l * 128, offawE,
              BS_ * S_, 128, C_, 0, stream);
        hipLaunchKernelGGL(msda_kernel, dim3(BS_ * S_), dim3(384), 0, stream,
                           value, offawE, eref, samp_bf, S_);
        gemm0(samp_bf, wOpE + (size_t)l * C_ * C_, e_op_b + (size_t)l * C_, x2,
              BS_ * S_, C_, C_, 0, stream);
        hipLaunchKernelGGL(ln_kernel, dim3(BS_ * S_), dim3(64), 0, stream,
                           x, x2, e_n1_g + (size_t)l * C_, e_n1_b + (size_t)l * C_, x, x_bf);
        gemm0(x_bf, wL1E + (size_t)l * DFFN_ * C_, e_l1_b + (size_t)l * DFFN_, hbuf_bf,
              BS_ * S_, DFFN_, C_, 1 | 2, stream);
        gemm0(hbuf_bf, wL2E + (size_t)l * C_ * DFFN_, e_l2_b + (size_t)l * C_, x2,
              BS_ * S_, C_, DFFN_, 0, stream);
        hipLaunchKernelGGL(ln_kernel, dim3(BS_ * S_), dim3(64), 0, stream,
                           x, x2, e_n2_g + (size_t)l * C_, e_n2_b + (size_t)l * C_, x, x_bf);
    }

    // ---- decoder init ----
    hipLaunchKernelGGL(init_y_kernel, dim3(decBlocks), dim3(256), 0, stream, qemb, y, y_bf);
    hipLaunchKernelGGL(decref_kernel, dim3((NQ_ * 3 + 63) / 64), dim3(64), 0, stream,
                       qemb, ref_w, ref_b, dref);

    for (int l = 0; l < 6; ++l) {
        const ushort* inw = wSaIn + (size_t)l * 3 * C_ * C_;
        const float* inb = dd_sa_in_b + (size_t)l * 3 * C_;

        // self-attention: qk = (y+qe) @ [Wq;Wk]^T, v = y @ Wv^T
        gemm1(y, qemb, 768, NQ_, inw, inb, qk, BS_ * NQ_, 768, C_, 0, stream);
        gemm0(y_bf, inw + (size_t)2 * C_ * C_, inb + 2 * C_, vpb, BS_ * NQ_, C_, C_, 0, stream);
        hipLaunchKernelGGL(mha_fused_kernel, dim3(5, 16), dim3(256), 0, stream, qk, vpb, samp_bf);
        gemm0(samp_bf, wSaOut + (size_t)l * C_ * C_, dd_sa_out_b + (size_t)l * C_, x2,
              BS_ * NQ_, C_, C_, 0, stream);
        hipLaunchKernelGGL(ln_kernel, dim3(BS_ * NQ_), dim3(64), 0, stream,
                           y, x2, dd_n2_g + (size_t)l * C_, dd_n2_b + (size_t)l * C_, y, y_bf);

        // cross deformable attention
        gemm0(x_bf, wVpD + (size_t)l * C_ * C_, dd_vp_b + (size_t)l * C_, value,
              BS_ * S_, C_, C_, 2, stream);
        gemm1(y, qemb, 768, NQ_, wOffawD + (size_t)l * 128 * C_, offawBd + l * 128, offawE,
              BS_ * NQ_, 128, C_, 0, stream);
        hipLaunchKernelGGL(msda_kernel, dim3(BS_ * NQ_), dim3(384), 0, stream,
                           value, offawE, dref, samp_bf, NQ_);
        gemm0(samp_bf, wOpD + (size_t)l * C_ * C_, dd_op_b + (size_t)l * C_, x2,
              BS_ * NQ_, C_, C_, 0, stream);
        hipLaunchKernelGGL(ln_kernel, dim3(BS_ * NQ_), dim3(64), 0, stream,
                           y, x2, dd_n1_g + (size_t)l * C_, dd_n1_b + (size_t)l * C_, y, y_bf);

        // FFN
        gemm0(y_bf, wL1D + (size_t)l * DFFN_ * C_, dd_l1_b + (size_t)l * DFFN_, hbuf_bf,
              BS_ * NQ_, DFFN_, C_, 1 | 2, stream);
        gemm0(hbuf_bf, wL2D + (size_t)l * C_ * DFFN_, dd_l2_b + (size_t)l * C_, x2,
              BS_ * NQ_, C_, DFFN_, 0, stream);
        float* lnout = (l == 5) ? (float*)d_out : y;
        hipLaunchKernelGGL(ln_kernel, dim3(BS_ * NQ_), dim3(64), 0, stream,
                           y, x2, dd_n3_g + (size_t)l * C_, dd_n3_b + (size_t)l * C_, lnout, y_bf);
    }
}

// Round 6
// 2224.951 us; speedup vs baseline: 1.0693x; 1.0693x over previous
//
#include <hip/hip_runtime.h>
#include <math.h>

#define BS_   2
#define S_    1728
#define C_    384
#define H_    8
#define HD_   48
#define DFFN_ 1536
#define NQ_   300
#define GD_   12

typedef __attribute__((ext_vector_type(8))) short short8;
typedef __attribute__((ext_vector_type(4))) float f32x4;

__device__ __forceinline__ ushort f2bf(float f) {
    union { float f; uint u; } v; v.f = f;
    uint u = v.u;
    uint r = (u + 0x7FFFu + ((u >> 16) & 1u)) >> 16;  // RNE
    return (ushort)r;
}
__device__ __forceinline__ float bf2f(ushort h) {
    union { uint u; float f; } v; v.u = ((uint)h) << 16;
    return v.f;
}

// ======================= one-shot fp32 -> bf16 weight conversion =======================
#define CT_N 34
struct ConvTab {
    const float* src[CT_N];
    ushort* dst[CT_N];
    int n[CT_N];
    int cum[CT_N + 1];
};
__global__ __launch_bounds__(256) void convall_kernel(ConvTab t)
{
    int blk = blockIdx.x;
    int e = 0;
    while (blk >= t.cum[e + 1]) ++e;
    int local = blk - t.cum[e];
    int base = local * 2048 + (int)threadIdx.x * 8;
    if (base >= t.n[e]) return;
    const float* s = t.src[e] + base;
    float4 a = *(const float4*)s;
    float4 b = *(const float4*)(s + 4);
    short8 o;
    o[0] = (short)f2bf(a.x); o[1] = (short)f2bf(a.y);
    o[2] = (short)f2bf(a.z); o[3] = (short)f2bf(a.w);
    o[4] = (short)f2bf(b.x); o[5] = (short)f2bf(b.y);
    o[6] = (short)f2bf(b.z); o[7] = (short)f2bf(b.w);
    *(short8*)(t.dst[e] + base) = o;
}

__global__ __launch_bounds__(256) void biaspack_kernel(
    const float* __restrict__ eoff, const float* __restrict__ eaw,
    const float* __restrict__ doff, const float* __restrict__ daw,
    float* __restrict__ be, float* __restrict__ bd)
{
    int i = blockIdx.x * 256 + threadIdx.x;
    if (i >= 768) return;
    int l = i >> 7, p = i & 127;
    be[i] = (p < 96) ? eoff[l * 96 + p] : eaw[l * 32 + p - 96];
    bd[i] = (p < 96) ? doff[l * 96 + p] : daw[l * 32 + p - 96];
}

// ======================= bf16 MFMA GEMM, tile 128x64, 4 waves of 64x32 =======================
// AMODE 0: A = bf16 ptr [M,K].  AMODE 1: A = f2bf(a0f[gm*K+k] + A1[(gm%rowmod)*lda1+k]).
// W bf16 [N,K]; bias fp32 [N]; out fp32 or bf16 (flags&2), relu (flags&1).
template<int AMODE>
__global__ __launch_bounds__(256) void gemm128_kernel(
    const void* __restrict__ Aptr, const float* __restrict__ A1,
    int lda1, int rowmod,
    const ushort* __restrict__ W, const float* __restrict__ bias,
    void* __restrict__ Co, int M, int N, int K, int flags)
{
    __shared__ __align__(16) ushort As[128][40];
    __shared__ __align__(16) ushort Ws[64][40];

    const int tid = threadIdx.x;
    const int m0 = blockIdx.y * 128;
    const int n0 = blockIdx.x * 64;

    const int arow = tid >> 1;
    const int acol = (tid & 1) * 16;
    const int gmA = m0 + arow;
    const int wrow = tid >> 2;
    const int wcol = (tid & 3) * 8;
    const int gnW = n0 + wrow;

    const int lane = tid & 63;
    const int w = tid >> 6;
    const int wm = (w >> 1) * 64;
    const int wn = (w & 1) * 32;
    const int fr = lane & 15;
    const int fq = lane >> 4;

    const ushort* Ab = (const ushort*)Aptr;
    const float* a0f = (const float*)Aptr;
    int a1row = 0;
    if (AMODE == 1 && gmA < M) a1row = gmA % rowmod;

    f32x4 acc[4][2] = {};

    short8 va[2] = {}, vw = {};
    if (gmA < M) {
        if (AMODE == 0) {
            va[0] = *(const short8*)(Ab + (size_t)gmA * K + acol);
            va[1] = *(const short8*)(Ab + (size_t)gmA * K + acol + 8);
        } else {
            const float* p0 = a0f + (size_t)gmA * K + acol;
            const float* p1 = A1 + (size_t)a1row * lda1 + acol;
            #pragma unroll
            for (int c = 0; c < 2; ++c)
                #pragma unroll
                for (int j = 0; j < 8; ++j)
                    va[c][j] = (short)f2bf(p0[c * 8 + j] + p1[c * 8 + j]);
        }
    }
    if (gnW < N) vw = *(const short8*)(W + (size_t)gnW * K + wcol);

    for (int k0 = 0; k0 < K; k0 += 32) {
        *(short8*)&As[arow][acol] = va[0];
        *(short8*)&As[arow][acol + 8] = va[1];
        *(short8*)&Ws[wrow][wcol] = vw;
        __syncthreads();
        if (k0 + 32 < K) {
            if (gmA < M) {
                if (AMODE == 0) {
                    va[0] = *(const short8*)(Ab + (size_t)gmA * K + k0 + 32 + acol);
                    va[1] = *(const short8*)(Ab + (size_t)gmA * K + k0 + 32 + acol + 8);
                } else {
                    const float* p0 = a0f + (size_t)gmA * K + k0 + 32 + acol;
                    const float* p1 = A1 + (size_t)a1row * lda1 + k0 + 32 + acol;
                    #pragma unroll
                    for (int c = 0; c < 2; ++c)
                        #pragma unroll
                        for (int j = 0; j < 8; ++j)
                            va[c][j] = (short)f2bf(p0[c * 8 + j] + p1[c * 8 + j]);
                }
            }
            if (gnW < N) vw = *(const short8*)(W + (size_t)gnW * K + k0 + 32 + wcol);
        }
        short8 af[4], bw[2];
        #pragma unroll
        for (int fi = 0; fi < 4; ++fi)
            af[fi] = *(const short8*)&As[wm + fi * 16 + fr][fq * 8];
        #pragma unroll
        for (int ni = 0; ni < 2; ++ni)
            bw[ni] = *(const short8*)&Ws[wn + ni * 16 + fr][fq * 8];
        #pragma unroll
        for (int fi = 0; fi < 4; ++fi)
            #pragma unroll
            for (int ni = 0; ni < 2; ++ni)
                acc[fi][ni] = __builtin_amdgcn_mfma_f32_16x16x32_bf16(
                    af[fi], bw[ni], acc[fi][ni], 0, 0, 0);
        __syncthreads();
    }

    const int relu = flags & 1;
    const int obf = flags & 2;
    float* Cf = (float*)Co;
    ushort* Ch = (ushort*)Co;
    #pragma unroll
    for (int fi = 0; fi < 4; ++fi) {
        #pragma unroll
        for (int ni = 0; ni < 2; ++ni) {
            int gn = n0 + wn + ni * 16 + fr;
            if (gn >= N) continue;
            float bv = bias[gn];
            #pragma unroll
            for (int j = 0; j < 4; ++j) {
                int gm = m0 + wm + fi * 16 + fq * 4 + j;
                if (gm >= M) continue;
                float v = acc[fi][ni][j] + bv;
                if (relu) v = fmaxf(v, 0.f);
                if (obf) Ch[(size_t)gm * N + gn] = f2bf(v);
                else     Cf[(size_t)gm * N + gn] = v;
            }
        }
    }
}

// ======================= bf16 MFMA GEMM, tile 128x128, 4 waves of 64x64 =======================
__global__ __launch_bounds__(256) void gemmbig_kernel(
    const ushort* __restrict__ A, const ushort* __restrict__ W,
    const float* __restrict__ bias, void* __restrict__ Co,
    int M, int N, int K, int flags)
{
    __shared__ __align__(16) ushort As[128][40];
    __shared__ __align__(16) ushort Ws[128][40];

    const int tid = threadIdx.x;
    const int m0 = blockIdx.y * 128;
    const int n0 = blockIdx.x * 128;

    const int srow = tid >> 1;
    const int scol = (tid & 1) * 16;
    const int gmA = m0 + srow;
    const int gnW = n0 + srow;

    const int lane = tid & 63;
    const int w = tid >> 6;
    const int wm = (w >> 1) * 64;
    const int wn = (w & 1) * 64;
    const int fr = lane & 15;
    const int fq = lane >> 4;

    f32x4 acc[4][4] = {};
    short8 va[2] = {}, vw[2] = {};
    if (gmA < M) {
        va[0] = *(const short8*)(A + (size_t)gmA * K + scol);
        va[1] = *(const short8*)(A + (size_t)gmA * K + scol + 8);
    }
    if (gnW < N) {
        vw[0] = *(const short8*)(W + (size_t)gnW * K + scol);
        vw[1] = *(const short8*)(W + (size_t)gnW * K + scol + 8);
    }

    for (int k0 = 0; k0 < K; k0 += 32) {
        *(short8*)&As[srow][scol] = va[0];
        *(short8*)&As[srow][scol + 8] = va[1];
        *(short8*)&Ws[srow][scol] = vw[0];
        *(short8*)&Ws[srow][scol + 8] = vw[1];
        __syncthreads();
        if (k0 + 32 < K) {
            if (gmA < M) {
                va[0] = *(const short8*)(A + (size_t)gmA * K + k0 + 32 + scol);
                va[1] = *(const short8*)(A + (size_t)gmA * K + k0 + 32 + scol + 8);
            }
            if (gnW < N) {
                vw[0] = *(const short8*)(W + (size_t)gnW * K + k0 + 32 + scol);
                vw[1] = *(const short8*)(W + (size_t)gnW * K + k0 + 32 + scol + 8);
            }
        }
        short8 af[4], bw[4];
        #pragma unroll
        for (int fi = 0; fi < 4; ++fi)
            af[fi] = *(const short8*)&As[wm + fi * 16 + fr][fq * 8];
        #pragma unroll
        for (int ni = 0; ni < 4; ++ni)
            bw[ni] = *(const short8*)&Ws[wn + ni * 16 + fr][fq * 8];
        #pragma unroll
        for (int fi = 0; fi < 4; ++fi)
            #pragma unroll
            for (int ni = 0; ni < 4; ++ni)
                acc[fi][ni] = __builtin_amdgcn_mfma_f32_16x16x32_bf16(
                    af[fi], bw[ni], acc[fi][ni], 0, 0, 0);
        __syncthreads();
    }

    const int relu = flags & 1;
    const int obf = flags & 2;
    float* Cf = (float*)Co;
    ushort* Ch = (ushort*)Co;
    #pragma unroll
    for (int fi = 0; fi < 4; ++fi) {
        #pragma unroll
        for (int ni = 0; ni < 4; ++ni) {
            int gn = n0 + wn + ni * 16 + fr;
            if (gn >= N) continue;
            float bv = bias[gn];
            #pragma unroll
            for (int j = 0; j < 4; ++j) {
                int gm = m0 + wm + fi * 16 + fq * 4 + j;
                if (gm >= M) continue;
                float v = acc[fi][ni][j] + bv;
                if (relu) v = fmaxf(v, 0.f);
                if (obf) Ch[(size_t)gm * N + gn] = f2bf(v);
                else     Cf[(size_t)gm * N + gn] = v;
            }
        }
    }
}

// ======================= fused MHA (decoder self-attn), LDS-free =======================
// qk bf16 [B*300][768] (Q cols 0..383, K cols 384..767); vpb bf16 [B*300][384]; out bf16.
// grid (19 q-tiles of 16, 16 b*h), 64 threads (1 wave). K/V read straight from L2 into
// MFMA B-fragments; only a 1.3KB pbuf for the P C->A layout transpose.
__global__ __launch_bounds__(64) void mha_fused_kernel(
    const ushort* __restrict__ qk, const ushort* __restrict__ vpb,
    ushort* __restrict__ out)
{
    __shared__ __align__(16) ushort pbuf[16][40];

    const int qt = blockIdx.x;    // 0..18
    const int bh = blockIdx.y;
    const int b = bh >> 3, h = bh & 7;
    const int lane = threadIdx.x;
    const int fr = lane & 15, fq = lane >> 4;

    // Q A-frag: row = fr (query qt*16+fr), k-slices d = 0..31 / 32..63 (d>=48 zero)
    int q = qt * 16 + fr; if (q > 299) q = 299;   // clamp: garbage rows masked at output
    const ushort* qrow = qk + ((size_t)(b * 300 + q)) * 768 + h * 48;
    short8 aq0 = *(const short8*)(qrow + fq * 8);
    short8 aq1 = (fq < 2) ? *(const short8*)(qrow + 32 + fq * 8) : short8{};

    // ---- scores: 19 key tiles of 16, direct global B-frags ----
    f32x4 sfr[20];
    #pragma unroll
    for (int t = 0; t < 19; ++t) {
        int key = t * 16 + fr; if (key > 299) key = 299;
        const ushort* krow = qk + ((size_t)(b * 300 + key)) * 768 + 384 + h * 48;
        short8 bk0 = *(const short8*)(krow + fq * 8);
        short8 bk1 = (fq < 2) ? *(const short8*)(krow + 32 + fq * 8) : short8{};
        f32x4 c = {};
        c = __builtin_amdgcn_mfma_f32_16x16x32_bf16(aq0, bk0, c, 0, 0, 0);
        c = __builtin_amdgcn_mfma_f32_16x16x32_bf16(aq1, bk1, c, 0, 0, 0);
        sfr[t] = c;
    }
    if (fr >= 12) { sfr[18][0] = sfr[18][1] = sfr[18][2] = sfr[18][3] = -1e30f; }
    sfr[19][0] = sfr[19][1] = sfr[19][2] = sfr[19][3] = -1e30f;  // keys 304..319

    const float scale = 0.14433756729740643f;  // 1/sqrt(48)
    float m[4], l[4];
    #pragma unroll
    for (int j = 0; j < 4; ++j) {
        float mm = -1e30f;
        #pragma unroll
        for (int t = 0; t < 20; ++t) mm = fmaxf(mm, sfr[t][j]);
        #pragma unroll
        for (int msk = 1; msk < 16; msk <<= 1) mm = fmaxf(mm, __shfl_xor(mm, msk));
        m[j] = mm;
    }
    #pragma unroll
    for (int j = 0; j < 4; ++j) {
        float ss = 0.f;
        #pragma unroll
        for (int t = 0; t < 20; ++t) {
            float p = __expf((sfr[t][j] - m[j]) * scale);
            sfr[t][j] = p;
            ss += p;
        }
        #pragma unroll
        for (int msk = 1; msk < 16; msk <<= 1) ss += __shfl_xor(ss, msk);
        l[j] = ss;
    }

    // ---- PV: 10 chunks of 32 keys; P via pbuf transpose, V^T direct global ----
    f32x4 o0 = {}, o1 = {}, o2 = {};
    const ushort* vb = vpb + (size_t)b * 300 * 384 + h * 48;
    for (int ch = 0; ch < 10; ++ch) {
        #pragma unroll
        for (int tt = 0; tt < 2; ++tt) {
            int t = 2 * ch + tt;
            #pragma unroll
            for (int j = 0; j < 4; ++j)
                pbuf[fq * 4 + j][tt * 16 + fr] = f2bf(sfr[t][j]);
        }
        asm volatile("s_waitcnt lgkmcnt(0)" ::: "memory");
        short8 pa = *(const short8*)&pbuf[fr][fq * 8];
        short8 bv[3];
        #pragma unroll
        for (int dt = 0; dt < 3; ++dt) {
            #pragma unroll
            for (int jj = 0; jj < 8; ++jj) {
                int key = ch * 32 + fq * 8 + jj; if (key > 299) key = 299; // P==0 there
                bv[dt][jj] = (short)vb[(size_t)key * 384 + dt * 16 + fr];
            }
        }
        o0 = __builtin_amdgcn_mfma_f32_16x16x32_bf16(pa, bv[0], o0, 0, 0, 0);
        o1 = __builtin_amdgcn_mfma_f32_16x16x32_bf16(pa, bv[1], o1, 0, 0, 0);
        o2 = __builtin_amdgcn_mfma_f32_16x16x32_bf16(pa, bv[2], o2, 0, 0, 0);
    }

    #pragma unroll
    for (int j = 0; j < 4; ++j) {
        int qq = qt * 16 + fq * 4 + j;
        if (qq >= 300) continue;
        float invl = 1.f / l[j];
        ushort* orow = out + ((size_t)(b * 300 + qq)) * 384 + h * 48;
        orow[fr]      = f2bf(o0[j] * invl);
        orow[16 + fr] = f2bf(o1[j] * invl);
        orow[32 + fr] = f2bf(o2[j] * invl);
    }
}

// ======================= LayerNorm(res + delta), C=384, one wave/row =======================
__global__ __launch_bounds__(64) void ln_kernel(
    const float* __restrict__ res, const float* __restrict__ delta,
    const float* __restrict__ g, const float* __restrict__ b,
    float* __restrict__ out, ushort* __restrict__ out_bf)
{
    const int row = blockIdx.x;
    const int lane = threadIdx.x;
    const float* r = res + (size_t)row * C_;
    const float* d = delta + (size_t)row * C_;
    float vals[6];
    float s = 0.f;
    #pragma unroll
    for (int i = 0; i < 6; ++i) {
        int c = lane + 64 * i;
        vals[i] = r[c] + d[c];
        s += vals[i];
    }
    #pragma unroll
    for (int off = 32; off; off >>= 1) s += __shfl_xor(s, off);
    float mean = s * (1.f / C_);
    float vs = 0.f;
    #pragma unroll
    for (int i = 0; i < 6; ++i) { float t = vals[i] - mean; vs += t * t; }
    #pragma unroll
    for (int off = 32; off; off >>= 1) vs += __shfl_xor(vs, off);
    float rstd = rsqrtf(vs * (1.f / C_) + 1e-5f);
    float* o = out + (size_t)row * C_;
    ushort* ob = out_bf + (size_t)row * C_;
    #pragma unroll
    for (int i = 0; i < 6; ++i) {
        int c = lane + 64 * i;
        float v = (vals[i] - mean) * rstd * g[c] + b[c];
        o[c] = v;
        ob[c] = f2bf(v);
    }
}

// ======================= MSDA sampling (bf16 value, merged off/aw input) =======================
__global__ __launch_bounds__(384) void msda_kernel(
    const ushort* __restrict__ value,  // (B,S,384) bf16
    const float* __restrict__ offaw,   // (B,Lq,128): 0..95 off, 96..127 aw
    const float* __restrict__ ref,     // (Lq,3)
    ushort* __restrict__ out,          // (B,Lq,384) bf16
    int Lq)
{
    const int bq = blockIdx.x;
    const int b = bq / Lq, qi = bq % Lq;
    const int t = threadIdx.x;
    const int h = t / HD_, c = t % HD_;

    const float* row = offaw + ((size_t)(b * Lq + qi)) * 128;
    const float* aw = row + 96 + h * 4;
    float a0 = aw[0], a1 = aw[1], a2 = aw[2], a3 = aw[3];
    float mx = fmaxf(fmaxf(a0, a1), fmaxf(a2, a3));
    float e0 = __expf(a0 - mx), e1 = __expf(a1 - mx), e2 = __expf(a2 - mx), e3 = __expf(a3 - mx);
    float inv = 1.f / (e0 + e1 + e2 + e3);
    float wgt[4] = { e0 * inv, e1 * inv, e2 * inv, e3 * inv };

    const float* off = row + h * 12;
    float rx = ref[qi * 3 + 0], ry = ref[qi * 3 + 1], rz = ref[qi * 3 + 2];
    const ushort* vb = value + (size_t)b * S_ * C_ + h * HD_ + c;

    float acc = 0.f;
    #pragma unroll
    for (int p = 0; p < 4; ++p) {
        float x = (rx + off[p * 3 + 0] * (1.f / GD_)) * GD_ - 0.5f;
        float y = (ry + off[p * 3 + 1] * (1.f / GD_)) * GD_ - 0.5f;
        float z = (rz + off[p * 3 + 2] * (1.f / GD_)) * GD_ - 0.5f;
        float x0f = floorf(x), y0f = floorf(y), z0f = floorf(z);
        float fx = x - x0f, fy = y - y0f, fz = z - z0f;
        int x0 = (int)x0f, y0 = (int)y0f, z0 = (int)z0f;
        float pv = 0.f;
        #pragma unroll
        for (int dz = 0; dz < 2; ++dz) {
            int zi = z0 + dz;
            if (zi < 0 || zi >= GD_) continue;
            float wz = dz ? fz : 1.f - fz;
            #pragma unroll
            for (int dy = 0; dy < 2; ++dy) {
                int yi = y0 + dy;
                if (yi < 0 || yi >= GD_) continue;
                float wy = dy ? fy : 1.f - fy;
                #pragma unroll
                for (int dx = 0; dx < 2; ++dx) {
                    int xi = x0 + dx;
                    if (xi < 0 || xi >= GD_) continue;
                    float wx = dx ? fx : 1.f - fx;
                    int s = (zi * GD_ + yi) * GD_ + xi;
                    pv += wz * wy * wx * bf2f(vb[(size_t)s * C_]);
                }
            }
        }
        acc += wgt[p] * pv;
    }
    out[((size_t)(b * Lq + qi)) * C_ + t] = f2bf(acc);
}

// ======================= misc =======================
__global__ __launch_bounds__(256) void prep_kernel(
    const float* __restrict__ srcs, const float* __restrict__ posin,
    const float* __restrict__ lvl, float* __restrict__ x, ushort* __restrict__ x_bf,
    float* __restrict__ pos)
{
    int idx = blockIdx.x * 256 + threadIdx.x;
    const int total = BS_ * S_ * C_;
    if (idx >= total) return;
    int c = idx % C_; int r = idx / C_;
    int s = r % S_;   int b = r / S_;
    size_t si = ((size_t)b * C_ + c) * S_ + s;
    float xv = srcs[si];
    x[idx] = xv;
    x_bf[idx] = f2bf(xv);
    pos[idx] = posin[si] + lvl[c];
}

__global__ __launch_bounds__(64) void encref_kernel(float* __restrict__ eref)
{
    int s = blockIdx.x * 64 + threadIdx.x;
    if (s >= S_) return;
    int w = s % GD_, h = (s / GD_) % GD_, d = s / (GD_ * GD_);
    eref[s * 3 + 0] = (w + 0.5f) / GD_;
    eref[s * 3 + 1] = (h + 0.5f) / GD_;
    eref[s * 3 + 2] = (d + 0.5f) / GD_;
}

__global__ __launch_bounds__(64) void decref_kernel(
    const float* __restrict__ qemb, const float* __restrict__ rw,
    const float* __restrict__ rb, float* __restrict__ dref)
{
    int idx = blockIdx.x * 64 + threadIdx.x;
    if (idx >= NQ_ * 3) return;
    int d = idx % 3, q = idx / 3;
    const float* qe = qemb + (size_t)q * 768;
    const float* w = rw + d * C_;
    float s = rb[d];
    for (int c = 0; c < C_; ++c) s = fmaf(qe[c], w[c], s);
    dref[idx] = 1.f / (1.f + __expf(-s));
}

__global__ __launch_bounds__(256) void init_y_kernel(
    const float* __restrict__ qemb, float* __restrict__ y, ushort* __restrict__ y_bf)
{
    int idx = blockIdx.x * 256 + threadIdx.x;
    const int total = BS_ * NQ_ * C_;
    if (idx >= total) return;
    int c = idx % C_; int q = (idx / C_) % NQ_;
    float v = qemb[(size_t)q * 768 + 384 + c];
    y[idx] = v;
    y_bf[idx] = f2bf(v);
}

// ======================= host =======================
static inline void gemm0(const ushort* A, const ushort* W, const float* bias, void* C,
                         int M, int N, int K, int flags, hipStream_t s)
{
    dim3 g((N + 63) / 64, (M + 127) / 128);
    hipLaunchKernelGGL(gemm128_kernel<0>, g, dim3(256), 0, s,
                       (const void*)A, (const float*)nullptr, 0, 1, W, bias, C, M, N, K, flags);
}
static inline void gemm1(const float* A0, const float* A1, int lda1, int rowmod,
                         const ushort* W, const float* bias, void* C,
                         int M, int N, int K, int flags, hipStream_t s)
{
    dim3 g((N + 63) / 64, (M + 127) / 128);
    hipLaunchKernelGGL(gemm128_kernel<1>, g, dim3(256), 0, s,
                       (const void*)A0, A1, lda1, rowmod, W, bias, C, M, N, K, flags);
}
static inline void gemmB(const ushort* A, const ushort* W, const float* bias, void* C,
                         int M, int N, int K, int flags, hipStream_t s)
{
    dim3 g((N + 127) / 128, (M + 127) / 128);
    hipLaunchKernelGGL(gemmbig_kernel, g, dim3(256), 0, s, A, W, bias, C, M, N, K, flags);
}

extern "C" void kernel_launch(void* const* d_in, const int* in_sizes, int n_in,
                              void* d_out, int out_size, void* d_ws, size_t ws_size,
                              hipStream_t stream)
{
    const float* srcs    = (const float*)d_in[0];
    const float* qemb    = (const float*)d_in[2];
    const float* posin   = (const float*)d_in[3];
    const float* lvl     = (const float*)d_in[4];
    const float* ref_w   = (const float*)d_in[5];
    const float* ref_b   = (const float*)d_in[6];
    const float* e_off_w = (const float*)d_in[7];
    const float* e_off_b = (const float*)d_in[8];
    const float* e_aw_w  = (const float*)d_in[9];
    const float* e_aw_b  = (const float*)d_in[10];
    const float* e_vp_w  = (const float*)d_in[11];
    const float* e_vp_b  = (const float*)d_in[12];
    const float* e_op_w  = (const float*)d_in[13];
    const float* e_op_b  = (const float*)d_in[14];
    const float* e_n1_g  = (const float*)d_in[15];
    const float* e_n1_b  = (const float*)d_in[16];
    const float* e_l1_w  = (const float*)d_in[17];
    const float* e_l1_b  = (const float*)d_in[18];
    const float* e_l2_w  = (const float*)d_in[19];
    const float* e_l2_b  = (const float*)d_in[20];
    const float* e_n2_g  = (const float*)d_in[21];
    const float* e_n2_b  = (const float*)d_in[22];
    const float* dd_off_w = (const float*)d_in[23];
    const float* dd_off_b = (const float*)d_in[24];
    const float* dd_aw_w  = (const float*)d_in[25];
    const float* dd_aw_b  = (const float*)d_in[26];
    const float* dd_vp_w  = (const float*)d_in[27];
    const float* dd_vp_b  = (const float*)d_in[28];
    const float* dd_op_w  = (const float*)d_in[29];
    const float* dd_op_b  = (const float*)d_in[30];
    const float* dd_n1_g  = (const float*)d_in[31];
    const float* dd_n1_b  = (const float*)d_in[32];
    const float* dd_l1_w  = (const float*)d_in[33];
    const float* dd_l1_b  = (const float*)d_in[34];
    const float* dd_l2_w  = (const float*)d_in[35];
    const float* dd_l2_b  = (const float*)d_in[36];
    const float* dd_n2_g  = (const float*)d_in[37];
    const float* dd_n2_b  = (const float*)d_in[38];
    const float* dd_sa_in_w  = (const float*)d_in[39];
    const float* dd_sa_in_b  = (const float*)d_in[40];
    const float* dd_sa_out_w = (const float*)d_in[41];
    const float* dd_sa_out_b = (const float*)d_in[42];
    const float* dd_n3_g  = (const float*)d_in[43];
    const float* dd_n3_b  = (const float*)d_in[44];

    // ---------- workspace ----------
    float* ws = (float*)d_ws;
    size_t o = 0;
    const size_t NXC = (size_t)BS_ * S_ * C_;   // 1,327,104
    const size_t NYC = (size_t)BS_ * NQ_ * C_;  // 230,400
    float* x      = ws + o; o += NXC;
    float* pos    = ws + o; o += NXC;
    float* x2     = ws + o; o += NXC;
    float* offawE = ws + o; o += (size_t)BS_ * S_ * 128;
    float* y      = ws + o; o += NYC;
    float* eref   = ws + o; o += (size_t)S_ * 3 + 64;
    float* dref   = ws + o; o += (size_t)NQ_ * 3 + 64;
    float* offawBe = ws + o; o += 768;
    float* offawBd = ws + o; o += 768;
    o = (o + 7) & ~(size_t)7;

    ushort* bws = (ushort*)(ws + o);
    size_t ob = 0;
    ushort* x_bf    = bws + ob; ob += NXC;
    ushort* samp_bf = bws + ob; ob += NXC;
    ushort* hbuf_bf = bws + ob; ob += (size_t)BS_ * S_ * DFFN_;
    ushort* y_bf    = bws + ob; ob += NYC;
    ushort* value   = bws + ob; ob += NXC;
    ushort* qk_bf   = bws + ob; ob += (size_t)BS_ * NQ_ * 768;
    ushort* vpb_bf  = bws + ob; ob += NYC;
    const size_t SZ_OFFAW = (size_t)6 * 128 * C_;
    const size_t SZ_SQ    = (size_t)6 * C_ * C_;
    const size_t SZ_L1    = (size_t)6 * DFFN_ * C_;
    ushort* wOffawE = bws + ob; ob += SZ_OFFAW;
    ushort* wOffawD = bws + ob; ob += SZ_OFFAW;
    ushort* wVpE = bws + ob; ob += SZ_SQ;
    ushort* wOpE = bws + ob; ob += SZ_SQ;
    ushort* wL1E = bws + ob; ob += SZ_L1;
    ushort* wL2E = bws + ob; ob += SZ_L1;
    ushort* wVpD = bws + ob; ob += SZ_SQ;
    ushort* wOpD = bws + ob; ob += SZ_SQ;
    ushort* wL1D = bws + ob; ob += SZ_L1;
    ushort* wL2D = bws + ob; ob += SZ_L1;
    ushort* wSaIn = bws + ob; ob += (size_t)6 * 3 * C_ * C_;
    ushort* wSaOut = bws + ob; ob += SZ_SQ;

    // ---------- one-shot weight conversion ----------
    ConvTab ct;
    int ne = 0;
    auto addent = [&](const float* s, ushort* d, int n) {
        ct.src[ne] = s; ct.dst[ne] = d; ct.n[ne] = n; ++ne;
    };
    for (int l = 0; l < 6; ++l) addent(e_off_w + (size_t)l * 96 * C_, wOffawE + (size_t)l * 128 * C_, 96 * C_);
    for (int l = 0; l < 6; ++l) addent(e_aw_w + (size_t)l * 32 * C_, wOffawE + (size_t)l * 128 * C_ + 96 * C_, 32 * C_);
    for (int l = 0; l < 6; ++l) addent(dd_off_w + (size_t)l * 96 * C_, wOffawD + (size_t)l * 128 * C_, 96 * C_);
    for (int l = 0; l < 6; ++l) addent(dd_aw_w + (size_t)l * 32 * C_, wOffawD + (size_t)l * 128 * C_ + 96 * C_, 32 * C_);
    addent(e_vp_w, wVpE, (int)SZ_SQ);
    addent(e_op_w, wOpE, (int)SZ_SQ);
    addent(e_l1_w, wL1E, (int)SZ_L1);
    addent(e_l2_w, wL2E, (int)SZ_L1);
    addent(dd_vp_w, wVpD, (int)SZ_SQ);
    addent(dd_op_w, wOpD, (int)SZ_SQ);
    addent(dd_l1_w, wL1D, (int)SZ_L1);
    addent(dd_l2_w, wL2D, (int)SZ_L1);
    addent(dd_sa_in_w, wSaIn, (int)((size_t)6 * 3 * C_ * C_));
    addent(dd_sa_out_w, wSaOut, (int)SZ_SQ);
    ct.cum[0] = 0;
    for (int e = 0; e < CT_N; ++e) ct.cum[e + 1] = ct.cum[e] + (ct.n[e] + 2047) / 2048;
    hipLaunchKernelGGL(convall_kernel, dim3(ct.cum[CT_N]), dim3(256), 0, stream, ct);
    hipLaunchKernelGGL(biaspack_kernel, dim3(3), dim3(256), 0, stream,
                       e_off_b, e_aw_b, dd_off_b, dd_aw_b, offawBe, offawBd);

    const int nEnc = BS_ * S_ * C_;
    const int encBlocks = (nEnc + 255) / 256;
    const int nDec = BS_ * NQ_ * C_;
    const int decBlocks = (nDec + 255) / 256;

    hipLaunchKernelGGL(prep_kernel, dim3(encBlocks), dim3(256), 0, stream, srcs, posin, lvl, x, x_bf, pos);
    hipLaunchKernelGGL(encref_kernel, dim3((S_ + 63) / 64), dim3(64), 0, stream, eref);

    // ---- encoder ----
    for (int l = 0; l < 6; ++l) {
        gemm0(x_bf, wVpE + (size_t)l * C_ * C_, e_vp_b + (size_t)l * C_, value,
              BS_ * S_, C_, C_, 2, stream);
        gemm1(x, pos, C_, BS_ * S_, wOffawE + (size_t)l * 128 * C_, offawBe + l * 128, offawE,
              BS_ * S_, 128, C_, 0, stream);
        hipLaunchKernelGGL(msda_kernel, dim3(BS_ * S_), dim3(384), 0, stream,
                           value, offawE, eref, samp_bf, S_);
        gemm0(samp_bf, wOpE + (size_t)l * C_ * C_, e_op_b + (size_t)l * C_, x2,
              BS_ * S_, C_, C_, 0, stream);
        hipLaunchKernelGGL(ln_kernel, dim3(BS_ * S_), dim3(64), 0, stream,
                           x, x2, e_n1_g + (size_t)l * C_, e_n1_b + (size_t)l * C_, x, x_bf);
        gemmB(x_bf, wL1E + (size_t)l * DFFN_ * C_, e_l1_b + (size_t)l * DFFN_, hbuf_bf,
              BS_ * S_, DFFN_, C_, 1 | 2, stream);
        gemm0(hbuf_bf, wL2E + (size_t)l * C_ * DFFN_, e_l2_b + (size_t)l * C_, x2,
              BS_ * S_, C_, DFFN_, 0, stream);
        hipLaunchKernelGGL(ln_kernel, dim3(BS_ * S_), dim3(64), 0, stream,
                           x, x2, e_n2_g + (size_t)l * C_, e_n2_b + (size_t)l * C_, x, x_bf);
    }

    // ---- decoder init ----
    hipLaunchKernelGGL(init_y_kernel, dim3(decBlocks), dim3(256), 0, stream, qemb, y, y_bf);
    hipLaunchKernelGGL(decref_kernel, dim3((NQ_ * 3 + 63) / 64), dim3(64), 0, stream,
                       qemb, ref_w, ref_b, dref);

    for (int l = 0; l < 6; ++l) {
        const ushort* inw = wSaIn + (size_t)l * 3 * C_ * C_;
        const float* inb = dd_sa_in_b + (size_t)l * 3 * C_;

        // self-attention: qk = (y+qe) @ [Wq;Wk]^T (bf16 out), v = y @ Wv^T (bf16 out)
        gemm1(y, qemb, 768, NQ_, inw, inb, qk_bf, BS_ * NQ_, 768, C_, 2, stream);
        gemm0(y_bf, inw + (size_t)2 * C_ * C_, inb + 2 * C_, vpb_bf, BS_ * NQ_, C_, C_, 2, stream);
        hipLaunchKernelGGL(mha_fused_kernel, dim3(19, 16), dim3(64), 0, stream,
                           qk_bf, vpb_bf, samp_bf);
        gemm0(samp_bf, wSaOut + (size_t)l * C_ * C_, dd_sa_out_b + (size_t)l * C_, x2,
              BS_ * NQ_, C_, C_, 0, stream);
        hipLaunchKernelGGL(ln_kernel, dim3(BS_ * NQ_), dim3(64), 0, stream,
                           y, x2, dd_n2_g + (size_t)l * C_, dd_n2_b + (size_t)l * C_, y, y_bf);

        // cross deformable attention
        gemm0(x_bf, wVpD + (size_t)l * C_ * C_, dd_vp_b + (size_t)l * C_, value,
              BS_ * S_, C_, C_, 2, stream);
        gemm1(y, qemb, 768, NQ_, wOffawD + (size_t)l * 128 * C_, offawBd + l * 128, offawE,
              BS_ * NQ_, 128, C_, 0, stream);
        hipLaunchKernelGGL(msda_kernel, dim3(BS_ * NQ_), dim3(384), 0, stream,
                           value, offawE, dref, samp_bf, NQ_);
        gemm0(samp_bf, wOpD + (size_t)l * C_ * C_, dd_op_b + (size_t)l * C_, x2,
              BS_ * NQ_, C_, C_, 0, stream);
        hipLaunchKernelGGL(ln_kernel, dim3(BS_ * NQ_), dim3(64), 0, stream,
                           y, x2, dd_n1_g + (size_t)l * C_, dd_n1_b + (size_t)l * C_, y, y_bf);

        // FFN
        gemm0(y_bf, wL1D + (size_t)l * DFFN_ * C_, dd_l1_b + (size_t)l * DFFN_, hbuf_bf,
              BS_ * NQ_, DFFN_, C_, 1 | 2, stream);
        gemm0(hbuf_bf, wL2D + (size_t)l * C_ * DFFN_, dd_l2_b + (size_t)l * C_, x2,
              BS_ * NQ_, C_, DFFN_, 0, stream);
        float* lnout = (l == 5) ? (float*)d_out : y;
        hipLaunchKernelGGL(ln_kernel, dim3(BS_ * NQ_), dim3(64), 0, stream,
                           y, x2, dd_n3_g + (size_t)l * C_, dd_n3_b + (size_t)l * C_, lnout, y_bf);
    }
}